// Round 13
// baseline (1280.495 us; speedup 1.0000x reference)
//
#include <hip/hip_runtime.h>
#include <stdint.h>

#define NHEADS 16
#define DIM 512
#define BWIN 4096
#define NTOK 49
#define M_TOTAL (BWIN * NTOK)          // 200704 = 784 * 256
#define QSCALE 0.17677669529663687f    // 32^-0.5

typedef __attribute__((ext_vector_type(4)))  float f32x4;
typedef __attribute__((ext_vector_type(16))) float f32x16;
typedef __attribute__((ext_vector_type(8)))  short s16x8;
typedef __attribute__((ext_vector_type(4)))  short s16x4;

__device__ __forceinline__ f32x4 mfma16(s16x8 a, s16x8 b, f32x4 c) {
    return __builtin_amdgcn_mfma_f32_16x16x32_bf16(a, b, c, 0, 0, 0);
}
__device__ __forceinline__ f32x16 mfma32(s16x8 a, s16x8 b, f32x16 c) {
    return __builtin_amdgcn_mfma_f32_32x32x16_bf16(a, b, c, 0, 0, 0);
}

// f32 -> bf16 round-nearest-even
__device__ __forceinline__ short f2bf(float f) {
    unsigned u = __builtin_bit_cast(unsigned, f);
    u += 0x7FFFu + ((u >> 16) & 1u);
    return (short)(u >> 16);
}

// pack two f32 -> 2x bf16 in one dword (lo = a, hi = b)
__device__ __forceinline__ unsigned cvtpk(float a, float b) {
    unsigned r;
    asm("v_cvt_pk_bf16_f32 %0, %1, %2" : "=v"(r) : "v"(a), "v"(b));
    return r;
}

__device__ __forceinline__ void gload16(const void* g, void* l) {
    __builtin_amdgcn_global_load_lds(
        (const __attribute__((address_space(1))) void*)g,
        (__attribute__((address_space(3))) void*)l, 16, 0, 0);
}

// ---------------- prep kernels ----------------

__global__ void k_prep_x(const float* __restrict__ x, short* __restrict__ xb) {
    int i = blockIdx.x * blockDim.x + threadIdx.x;
    int stride = gridDim.x * blockDim.x;
    const int n4 = M_TOTAL * DIM / 4;
    for (; i < n4; i += stride) {
        f32x4 v = ((const f32x4*)x)[i];
        s16x4 o;
        o[0] = f2bf(v[0]); o[1] = f2bf(v[1]); o[2] = f2bf(v[2]); o[3] = f2bf(v[3]);
        ((s16x4*)xb)[i] = o;
    }
}

__global__ void k_prep_w(const float* __restrict__ src, short* __restrict__ dst,
                         int n, int scale_lim) {
    int i = blockIdx.x * blockDim.x + threadIdx.x;
    int stride = gridDim.x * blockDim.x;
    for (; i < n; i += stride) {
        float v = src[i];
        if (i < scale_lim) v *= QSCALE;
        dst[i] = f2bf(v);
    }
}

// bmT[w64][h][j][i64] = bias_table[rel(i,j)*16+h] + mask[w64][i*49+j]   (i padded to 64)
__global__ void k_prep_bm(const float* __restrict__ btab, const float* __restrict__ mask,
                          float* __restrict__ bmT) {
    int idx = blockIdx.x * blockDim.x + threadIdx.x;
    int stride = gridDim.x * blockDim.x;
    const int n = 64 * NHEADS * 49 * 64;
    for (; idx < n; idx += stride) {
        int i = idx & 63;
        int rest = idx >> 6;
        int j = rest % 49;
        int wh = rest / 49;
        int head = wh & 15;
        int w64 = wh >> 4;
        float v = 0.f;
        if (i < 49) {
            int ridx = (i / 7 - j / 7 + 6) * 13 + (i % 7 - j % 7 + 6);
            v = btab[ridx * 16 + head] + mask[(w64 * 49 + i) * 49 + j];
        }
        bmT[idx] = v;
    }
}

// ---------------- GEMM: C[M,N] = A[M,512] @ B^T[N,512] + bias ----------------
// 256x256 tile, BK=64, 8 waves (2Mx4N), 8-phase schedule with fragment
// software pipeline: phase p+1's A-frag ds_reads issue UNDER phase p's MFMA
// cluster via counted lgkmcnt(8) (FIFO) + sched_barrier pinning; B uses a
// single shared set S re-read per phase (VGPR stays at 2 waves/SIMD).
// Stage order {ph0: Ah0'+Bh0', ph1: Bh1', ph2: Ah1'}; uniform vmcnt(6)
// retires each region one phase before its first ds_read (FIFO-verified;
// tail kt=7: ph0 VMW(2) retires Bh0/Bh1(7), ph1 VMW(0) drains Ah1(7)).
// MODE 0: qkv -> bf16 head-major planes [n/32][M][32] via LDS-bounce epilogue
// MODE 1: proj -> f32 out, stride 512, direct stores
template <int MODE>
__global__ __launch_bounds__(512, 2) void k_gemm(
    const short* __restrict__ A, const short* __restrict__ B,
    const float* __restrict__ bias, void* __restrict__ C,
    int ntiles, int nwg) {
    __shared__ short lA[2][256 * 64];   // 64 KB
    __shared__ short lB[2][256 * 64];   // 64 KB
    const int K = 512;
    const size_t MP = M_TOTAL;

    int bid   = blockIdx.x;
    int chunk = nwg >> 3;                      // nwg % 8 == 0
    int wg    = (bid & 7) * chunk + (bid >> 3);
    int mt = wg / ntiles;
    int nt = wg - mt * ntiles;

    int t = threadIdx.x;
    int lane = t & 63, wid = t >> 6;
    int l15 = lane & 15, g = (lane >> 4) & 3;
    int wr = wid >> 2, wc = wid & 3;           // wave tile: rows wr*128, cols wc*64

    const short* aT = A + (size_t)mt * 256 * K;
    const short* bT = B + (size_t)nt * 256 * K;

    f32x4 acc[8][4] = {};
    s16x8 afA[4][2], afB[4][2], S[2][2];

// stage half-tile (128 rows x 64 K, 2 gloads): A halves by row bit6, B by bit5
#define STAGE_A(buf, H, kt) do {                                               \
    _Pragma("unroll") for (int j = 0; j < 2; j++) {                            \
        int r_ = j * 128 + (H) * 64 + (t >> 3);                                \
        int sc_ = (t & 7) ^ (r_ & 7);                                          \
        gload16(aT + (size_t)r_ * K + (kt) * 64 + sc_ * 8,                     \
                &lA[buf][r_ * 64 + (t & 7) * 8]);                              \
    } } while (0)

#define STAGE_B(buf, H, kt) do {                                               \
    _Pragma("unroll") for (int j = 0; j < 2; j++) {                            \
        int u_ = j * 64 + (t >> 3);                                            \
        int r_ = ((u_ >> 5) << 6) | ((H) << 5) | (u_ & 31);                    \
        int sc_ = (t & 7) ^ (r_ & 7);                                          \
        gload16(bT + (size_t)r_ * K + (kt) * 64 + sc_ * 8,                     \
                &lB[buf][r_ * 64 + (t & 7) * 8]);                              \
    } } while (0)

// A-frag set read (8 x ds_read_b128, XOR-swizzled)
#define LDAF(DST, MH, buf) do {                                                \
    const short* pa_ = &lA[buf][(wr * 128 + (MH) * 64 + l15) * 64];            \
    _Pragma("unroll") for (int mi = 0; mi < 4; mi++)                           \
    _Pragma("unroll") for (int ks = 0; ks < 2; ks++)                           \
        DST[mi][ks] = *(const s16x8*)(pa_ + mi * 1024 +                        \
                                      (((ks * 4 + g) ^ (l15 & 7)) * 8));       \
    } while (0)

// B-frag shared set read (4 x ds_read_b128)
#define LDBS(NH, buf) do {                                                     \
    const short* pb_ = &lB[buf][(wc * 64 + (NH) * 32 + l15) * 64];             \
    _Pragma("unroll") for (int nj = 0; nj < 2; nj++)                           \
    _Pragma("unroll") for (int ks = 0; ks < 2; ks++)                           \
        S[nj][ks] = *(const s16x8*)(pb_ + nj * 1024 +                          \
                                    (((ks * 4 + g) ^ (l15 & 7)) * 8));         \
    } while (0)

#define MMQ2(ASET, MH, NH) do {                                                \
    __builtin_amdgcn_s_setprio(1);                                             \
    _Pragma("unroll") for (int ks = 0; ks < 2; ks++)                           \
    _Pragma("unroll") for (int mi = 0; mi < 4; mi++)                           \
    _Pragma("unroll") for (int nj = 0; nj < 2; nj++)                           \
        acc[(MH) * 4 + mi][(NH) * 2 + nj] =                                    \
            mfma16(ASET[mi][ks], S[nj][ks], acc[(MH) * 4 + mi][(NH) * 2 + nj]);\
    __builtin_amdgcn_s_setprio(0);                                             \
} while (0)

#define BAR() __builtin_amdgcn_s_barrier()
#define SB0() __builtin_amdgcn_sched_barrier(0)
#define LGK0 do { asm volatile("s_waitcnt lgkmcnt(0)" ::: "memory"); SB0(); } while (0)
#define LGK8 do { asm volatile("s_waitcnt lgkmcnt(8)" ::: "memory"); SB0(); } while (0)
#define VMW(n) asm volatile("s_waitcnt vmcnt(" #n ")" ::: "memory")

    // prologue: stage tile 0 fully; prefetch A0(0) frags (stay outstanding)
    STAGE_A(0, 0, 0);
    STAGE_B(0, 0, 0);
    STAGE_B(0, 1, 0);
    STAGE_A(0, 1, 0);
    VMW(6);                       // Ah0(0) landed
    BAR();
    LDAF(afA, 0, 0);              // 8 ds_reads, drained at ph0's LGK0

    for (int kt = 0; kt < 8; ++kt) {
        const int cur = kt & 1, nxt = cur ^ 1;
        const bool st = kt < 7;
        // ---- ph0: MFMA(A0,B0) ; stage Ah0'(U1), Bh0'(U2)
        if (st) { STAGE_A(nxt, 0, kt + 1); STAGE_B(nxt, 0, kt + 1); VMW(6); }
        else VMW(2);              // tail: retire Bh0(7), Bh1(7)
        BAR();
        LDBS(0, cur);             // B0 (region retired by the VMW above)
        LGK0;                     // drains afA prefetch + S
        MMQ2(afA, 0, 0);
        BAR();
        // ---- ph1: MFMA(A0,B1) ; stage Bh1'(U3) ; prefetch afB = A1(cur)
        if (st) { STAGE_B(nxt, 1, kt + 1); VMW(6); }
        else VMW(0);              // tail: drain Ah1(7)
        BAR();
        LDBS(1, cur);
        SB0();                    // pin order: S reads BEFORE afB reads (FIFO)
        LDAF(afB, 1, cur);
        LGK8;                     // retires S; afB stays outstanding under MFMA
        MMQ2(afA, 0, 1);
        BAR();
        // ---- ph2: MFMA(A1,B1) ; stage Ah1'(U4)
        if (st) STAGE_A(nxt, 1, kt + 1);
        BAR();
        LGK0;                     // drains afB
        MMQ2(afB, 1, 1);
        BAR();
        // ---- ph3: MFMA(A1,B0) ; prefetch afA' = A0(kt+1) from buf nxt
        if (st) VMW(6);           // retires Ah0'(U1) -> afA' read safe
        BAR();
        LDBS(0, cur);             // re-read B0 (cur region untouched)
        if (st) {
            SB0();
            LDAF(afA, 0, nxt);    // afA' outstanding under MFMA + across BAR
            LGK8;                 // retires S only
        } else {
            LGK0;
        }
        MMQ2(afB, 1, 0);
        BAR();
    }

#undef STAGE_A
#undef STAGE_B
#undef LDAF
#undef LDBS
#undef MMQ2
#undef SB0
#undef VMW

    int m0 = mt * 256 + wr * 128;
    int n0 = nt * 256 + wc * 64;

    if (MODE == 0) {
        // bounce C through dead LDS: per-wave 128x64 bf16 region (16 KB)
        short* region = (wid < 4) ? (&lA[0][0] + wid * 8192)
                                  : (&lB[0][0] + (wid - 4) * 8192);
#pragma unroll
        for (int a = 0; a < 4; a++) {
            int co = (a >> 1) * 32 + (a & 1) * 16;       // col offset of acc[.][a]
            int n = n0 + co + l15;
            float bv = bias[n];
            if (n < 512) bv *= QSCALE;
            int w16 = (co >> 3) + (l15 >> 3);
#pragma unroll
            for (int mi = 0; mi < 8; mi++)
#pragma unroll
                for (int r = 0; r < 4; r++) {
                    int row = mi * 16 + g * 4 + r;
                    region[row * 64 + ((w16 ^ (row & 7)) * 8) + (l15 & 7)] =
                        f2bf(acc[mi][a][r] + bv);
                }
        }
        // per-wave private region; compiler inserts lgkmcnt for RAW
#pragma unroll
        for (int p = 0; p < 2; p++) {
            int plane = (n0 >> 5) + p;                   // n/32 = which*16+head
            short* dst = (short*)C + ((size_t)plane * MP + m0) * 32;
#pragma unroll
            for (int i = 0; i < 8; i++) {
                int f = i * 64 + lane;
                int row = f >> 2, c = f & 3;
                s16x8 v = *(const s16x8*)(region + row * 64 +
                                          (((p * 4 + c) ^ (row & 7)) * 8));
                *(s16x8*)(dst + (size_t)f * 8) = v;      // coalesced 16B
            }
        }
    } else {
#pragma unroll
        for (int a = 0; a < 4; a++) {
            int co = (a >> 1) * 32 + (a & 1) * 16;
            int n = n0 + co + l15;
            float bv = bias[n];
#pragma unroll
            for (int mi = 0; mi < 8; mi++)
#pragma unroll
                for (int r = 0; r < 4; r++) {
                    int m = m0 + mi * 16 + g * 4 + r;
                    ((float*)C)[(size_t)m * 512 + n] = acc[mi][a][r] + bv;
                }
        }
    }
}

// ---------------- attention (LDS-free, 32x32 MFMA + shfl P-transpose) --------
// qkv head-major: [which][head][MP][32]. One wave per (window, head).
__global__ __launch_bounds__(256, 4) void k_attn(
    const short* __restrict__ qkv, const float* __restrict__ bmT,
    short* __restrict__ ao) {
    int wid = threadIdx.x >> 6, lane = threadIdx.x & 63;
    int p = blockIdx.x * 4 + wid;
    int w = p >> 4, head = p & 15;
    int l31 = lane & 31, h = lane >> 5;
    const size_t MP = M_TOTAL;

    const short* qb = qkv + ((size_t)head * MP + w * 49) * 32;
    const short* kb = qb + (size_t)16 * MP * 32;
    const short* vb = qb + (size_t)32 * MP * 32;

    // q/k fragments for S^T = K @ Q^T (A = K: row j; B = Q^T: col i; k = d)
    s16x8 qf[2][2], kf[2][2];
#pragma unroll
    for (int t = 0; t < 2; t++) {
        int row = t * 32 + l31;
#pragma unroll
        for (int s = 0; s < 2; s++) {
            qf[t][s] = *(const s16x8*)(qb + row * 32 + 16 * s + 8 * h);
            kf[t][s] = *(const s16x8*)(kb + row * 32 + 16 * s + 8 * h);
        }
    }

    // V B-fragments: lane: col d = l31, k-rows j = 16*jc + 8h + e
    union U8 { short s[8]; s16x8 v; };
    U8 vf[4];
#pragma unroll
    for (int jc = 0; jc < 4; jc++)
#pragma unroll
        for (int e = 0; e < 8; e++)
            vf[jc].s[e] = vb[(16 * jc + 8 * h + e) * 32 + l31];

    // S^T tiles: st[jt][it], elem r: j = 32jt + (r&3)+8(r>>2)+4h, i = 32it + l31
    f32x16 st[2][2] = {};
#pragma unroll
    for (int s = 0; s < 2; s++)
#pragma unroll
        for (int jt = 0; jt < 2; jt++)
#pragma unroll
            for (int it = 0; it < 2; it++)
                st[jt][it] = mfma32(kf[jt][s], qf[it][s], st[jt][it]);

    // + (rel-pos bias + mask), padded j -> -1e30. bmT coalesced over i.
    const float* bs = bmT + ((size_t)((w & 63) * NHEADS + head)) * 3136 + l31;
#pragma unroll
    for (int jt = 0; jt < 2; jt++)
#pragma unroll
        for (int it = 0; it < 2; it++)
#pragma unroll
            for (int r = 0; r < 16; r++) {
                int j = 32 * jt + (r & 3) + 8 * (r >> 2) + 4 * h;
                if (j < 49) st[jt][it][r] += bs[j * 64 + 32 * it];
                else        st[jt][it][r] = -1e30f;
            }

    // softmax over j (per column i): 32 in-lane values + cross-half xor32
    float inv[2];
#pragma unroll
    for (int it = 0; it < 2; it++) {
        float mx = -1e30f;
#pragma unroll
        for (int jt = 0; jt < 2; jt++)
#pragma unroll
            for (int r = 0; r < 16; r++) mx = fmaxf(mx, st[jt][it][r]);
        mx = fmaxf(mx, __shfl_xor(mx, 32));
        float sum = 0.f;
#pragma unroll
        for (int jt = 0; jt < 2; jt++)
#pragma unroll
            for (int r = 0; r < 16; r++) {
                float e = __expf(st[jt][it][r] - mx);
                st[jt][it][r] = e;
                sum += e;
            }
        sum += __shfl_xor(sum, 32);
        inv[it] = 1.0f / sum;
    }

    // PV: P A-frags built in-register (cvt_pk + shfl_xor(32) cross-half fetch)
    f32x16 oacc[2] = {};
#pragma unroll
    for (int jc = 0; jc < 4; jc++) {
        const int jt = jc >> 1, rb = 8 * (jc & 1);
#pragma unroll
        for (int it = 0; it < 2; it++) {
            float iv = inv[it];
            unsigned pk0  = cvtpk(st[jt][it][rb + 0] * iv, st[jt][it][rb + 1] * iv);
            unsigned pk0b = cvtpk(st[jt][it][rb + 2] * iv, st[jt][it][rb + 3] * iv);
            unsigned pk1  = cvtpk(st[jt][it][rb + 4] * iv, st[jt][it][rb + 5] * iv);
            unsigned pk1b = cvtpk(st[jt][it][rb + 6] * iv, st[jt][it][rb + 7] * iv);
            unsigned o0  = __shfl_xor(pk0, 32);
            unsigned o0b = __shfl_xor(pk0b, 32);
            unsigned o1  = __shfl_xor(pk1, 32);
            unsigned o1b = __shfl_xor(pk1b, 32);
            union { unsigned d[4]; s16x8 v; } pa;
            pa.d[0] = h ? o1  : pk0;
            pa.d[1] = h ? o1b : pk0b;
            pa.d[2] = h ? pk1 : o0;
            pa.d[3] = h ? pk1b : o0b;
            oacc[it] = mfma32(pa.v, vf[jc].v, oacc[it]);
        }
    }

    // store: col d = l31, row i = 32it + 4h + (r&3) + 8(r>>2)
    short* ob = ao + (size_t)w * 49 * 512 + head * 32 + l31;
#pragma unroll
    for (int it = 0; it < 2; it++)
#pragma unroll
        for (int r = 0; r < 16; r++) {
            int i = 32 * it + 4 * h + (r & 3) + 8 * (r >> 2);
            if (i < 49) ob[(size_t)i * 512] = f2bf(oacc[it][r]);
        }
}

// ---------------- launch ----------------

extern "C" void kernel_launch(void* const* d_in, const int* in_sizes, int n_in,
                              void* d_out, int out_size, void* d_ws, size_t ws_size,
                              hipStream_t stream) {
    const float* x     = (const float*)d_in[0];
    const float* mask  = (const float*)d_in[1];
    const float* Wqkv  = (const float*)d_in[2];
    const float* bqkv  = (const float*)d_in[3];
    const float* btab  = (const float*)d_in[4];
    const float* Wproj = (const float*)d_in[5];
    const float* bproj = (const float*)d_in[6];
    float* out = (float*)d_out;

    char* ws = (char*)d_ws;
    size_t off = 0;
    short* xb     = (short*)(ws + off); off += (size_t)M_TOTAL * 512 * 2;          // reused as ao
    short* qkvb   = (short*)(ws + off); off += (size_t)48 * M_TOTAL * 32 * 2 + 65536;  // head-major + pad
    short* Wqkvb  = (short*)(ws + off); off += (size_t)1536 * 512 * 2;
    short* Wprojb = (short*)(ws + off); off += (size_t)512 * 512 * 2;
    float* bmT    = (float*)(ws + off); off += (size_t)64 * NHEADS * 49 * 64 * 4;  // 12.85 MB
    short* ao = xb;   // alias: xb dead after qkv GEMM

    k_prep_x<<<2048, 256, 0, stream>>>(x, xb);
    k_prep_w<<<1536, 256, 0, stream>>>(Wqkv, Wqkvb, 1536 * 512, 512 * 512);
    k_prep_w<<<512, 256, 0, stream>>>(Wproj, Wprojb, 512 * 512, 0);
    k_prep_bm<<<2048, 256, 0, stream>>>(btab, mask, bmT);

    k_gemm<0><<<4704, 512, 0, stream>>>(xb, Wqkvb, bqkv, qkvb, 6, 4704);
    k_attn<<<16384, 256, 0, stream>>>(qkvb, bmT, ao);
    k_gemm<1><<<1568, 512, 0, stream>>>(ao, Wprojb, bproj, out, 2, 1568);
}

// Round 14
// 1047.177 us; speedup vs baseline: 1.2228x; 1.2228x over previous
//
#include <hip/hip_runtime.h>
#include <stdint.h>

#define NHEADS 16
#define DIM 512
#define BWIN 4096
#define NTOK 49
#define M_TOTAL (BWIN * NTOK)          // 200704 = 784 * 256
#define QSCALE 0.17677669529663687f    // 32^-0.5

typedef __attribute__((ext_vector_type(4)))  float f32x4;
typedef __attribute__((ext_vector_type(16))) float f32x16;
typedef __attribute__((ext_vector_type(8)))  short s16x8;
typedef __attribute__((ext_vector_type(4)))  short s16x4;

__device__ __forceinline__ f32x4 mfma16(s16x8 a, s16x8 b, f32x4 c) {
    return __builtin_amdgcn_mfma_f32_16x16x32_bf16(a, b, c, 0, 0, 0);
}
__device__ __forceinline__ f32x16 mfma32(s16x8 a, s16x8 b, f32x16 c) {
    return __builtin_amdgcn_mfma_f32_32x32x16_bf16(a, b, c, 0, 0, 0);
}

// f32 -> bf16 round-nearest-even
__device__ __forceinline__ short f2bf(float f) {
    unsigned u = __builtin_bit_cast(unsigned, f);
    u += 0x7FFFu + ((u >> 16) & 1u);
    return (short)(u >> 16);
}

// pack two f32 -> 2x bf16 in one dword (lo = a, hi = b)
__device__ __forceinline__ unsigned cvtpk(float a, float b) {
    unsigned r;
    asm("v_cvt_pk_bf16_f32 %0, %1, %2" : "=v"(r) : "v"(a), "v"(b));
    return r;
}

__device__ __forceinline__ void gload16(const void* g, void* l) {
    __builtin_amdgcn_global_load_lds(
        (const __attribute__((address_space(1))) void*)g,
        (__attribute__((address_space(3))) void*)l, 16, 0, 0);
}

// ---------------- prep kernels ----------------

__global__ void k_prep_x(const float* __restrict__ x, short* __restrict__ xb) {
    int i = blockIdx.x * blockDim.x + threadIdx.x;
    int stride = gridDim.x * blockDim.x;
    const int n4 = M_TOTAL * DIM / 4;
    for (; i < n4; i += stride) {
        f32x4 v = ((const f32x4*)x)[i];
        s16x4 o;
        o[0] = f2bf(v[0]); o[1] = f2bf(v[1]); o[2] = f2bf(v[2]); o[3] = f2bf(v[3]);
        ((s16x4*)xb)[i] = o;
    }
}

__global__ void k_prep_w(const float* __restrict__ src, short* __restrict__ dst,
                         int n, int scale_lim) {
    int i = blockIdx.x * blockDim.x + threadIdx.x;
    int stride = gridDim.x * blockDim.x;
    for (; i < n; i += stride) {
        float v = src[i];
        if (i < scale_lim) v *= QSCALE;
        dst[i] = f2bf(v);
    }
}

// bmF: fragment-ordered bias+mask, layout [w64][head][jt][it][lane][r16] f32.
// For lane (l31 = lane&31, h = lane>>5), elem r: i = 32*it + l31,
// j = 32*jt + (r&3) + 8*(r>>2) + 4*h. Bakes the padding mask in:
// j>=49 -> -1e30 (softmax kill), else i>=49 -> 0 (dead column), else bias+mask.
__global__ void k_prep_bm(const float* __restrict__ btab, const float* __restrict__ mask,
                          float* __restrict__ bmF) {
    int idx = blockIdx.x * blockDim.x + threadIdx.x;
    int stride = gridDim.x * blockDim.x;
    const int n = 64 * NHEADS * 2 * 2 * 64 * 16;   // 4.19M floats, 16.8 MB
    for (; idx < n; idx += stride) {
        int r    = idx & 15;
        int lane = (idx >> 4) & 63;
        int it   = (idx >> 10) & 1;
        int jt   = (idx >> 11) & 1;
        int head = (idx >> 12) & 15;
        int w64  = idx >> 16;
        int l31 = lane & 31, h = lane >> 5;
        int i = 32 * it + l31;
        int j = 32 * jt + (r & 3) + 8 * (r >> 2) + 4 * h;
        float v;
        if (j >= 49)      v = -1e30f;
        else if (i >= 49) v = 0.f;
        else {
            int ridx = (i / 7 - j / 7 + 6) * 13 + (i % 7 - j % 7 + 6);
            v = btab[ridx * 16 + head] + mask[(w64 * 49 + i) * 49 + j];
        }
        bmF[idx] = v;
    }
}

// ---------------- GEMM: C[M,N] = A[M,512] @ B^T[N,512] + bias ----------------
// EXACT round-6 kernel (best measured: 435 us, MfmaUtil 31.4, conflicts 0).
// 256x256 tile, BK=64, 8 waves (2Mx4N), 4 phases/K-tile, stage-in-phase
// {Ah0,Bh0,Bh1,Ah1}, vmcnt(4) steady / vmcnt(0) tail, 2 barriers/phase.
// MODE 0: qkv -> bf16 head-major planes [n/32][M][32] via LDS-bounce epilogue
// MODE 1: proj -> f32 out, stride 512, direct stores
template <int MODE>
__global__ __launch_bounds__(512, 2) void k_gemm(
    const short* __restrict__ A, const short* __restrict__ B,
    const float* __restrict__ bias, void* __restrict__ C,
    int ntiles, int nwg) {
    __shared__ short lA[2][256 * 64];   // 64 KB
    __shared__ short lB[2][256 * 64];   // 64 KB
    const int K = 512;
    const size_t MP = M_TOTAL;

    int bid   = blockIdx.x;
    int chunk = nwg >> 3;                      // nwg % 8 == 0
    int wg    = (bid & 7) * chunk + (bid >> 3);
    int mt = wg / ntiles;
    int nt = wg - mt * ntiles;

    int t = threadIdx.x;
    int lane = t & 63, wid = t >> 6;
    int l15 = lane & 15, g = (lane >> 4) & 3;
    int wr = wid >> 2, wc = wid & 3;           // wave tile: rows wr*128, cols wc*64

    const short* aT = A + (size_t)mt * 256 * K;
    const short* bT = B + (size_t)nt * 256 * K;

    f32x4 acc[8][4] = {};
    s16x8 af[4][2], bf0[2][2], bf1[2][2];

#define STAGE_A(buf, H, kt) do {                                               \
    _Pragma("unroll") for (int j = 0; j < 2; j++) {                            \
        int r_ = j * 128 + (H) * 64 + (t >> 3);                                \
        int sc_ = (t & 7) ^ (r_ & 7);                                          \
        gload16(aT + (size_t)r_ * K + (kt) * 64 + sc_ * 8,                     \
                &lA[buf][r_ * 64 + (t & 7) * 8]);                              \
    } } while (0)

#define STAGE_B(buf, H, kt) do {                                               \
    _Pragma("unroll") for (int j = 0; j < 2; j++) {                            \
        int u_ = j * 64 + (t >> 3);                                            \
        int r_ = ((u_ >> 5) << 6) | ((H) << 5) | (u_ & 31);                    \
        int sc_ = (t & 7) ^ (r_ & 7);                                          \
        gload16(bT + (size_t)r_ * K + (kt) * 64 + sc_ * 8,                     \
                &lB[buf][r_ * 64 + (t & 7) * 8]);                              \
    } } while (0)

#define LDA(MH, cur) do {                                                      \
    const short* pa_ = &lA[cur][(wr * 128 + (MH) * 64 + l15) * 64];            \
    _Pragma("unroll") for (int mi = 0; mi < 4; mi++)                           \
    _Pragma("unroll") for (int ks = 0; ks < 2; ks++)                           \
        af[mi][ks] = *(const s16x8*)(pa_ + mi * 1024 +                         \
                                     (((ks * 4 + g) ^ (l15 & 7)) * 8));        \
    } while (0)

#define LDB(BF, NH, cur) do {                                                  \
    const short* pb_ = &lB[cur][(wc * 64 + (NH) * 32 + l15) * 64];             \
    _Pragma("unroll") for (int nj = 0; nj < 2; nj++)                           \
    _Pragma("unroll") for (int ks = 0; ks < 2; ks++)                           \
        BF[nj][ks] = *(const s16x8*)(pb_ + nj * 1024 +                         \
                                     (((ks * 4 + g) ^ (l15 & 7)) * 8));        \
    } while (0)

#define MMQ(BF, MH, NH) do {                                                   \
    __builtin_amdgcn_s_setprio(1);                                             \
    _Pragma("unroll") for (int ks = 0; ks < 2; ks++)                           \
    _Pragma("unroll") for (int mi = 0; mi < 4; mi++)                           \
    _Pragma("unroll") for (int nj = 0; nj < 2; nj++)                           \
        acc[(MH) * 4 + mi][(NH) * 2 + nj] =                                    \
            mfma16(af[mi][ks], BF[nj][ks], acc[(MH) * 4 + mi][(NH) * 2 + nj]); \
    __builtin_amdgcn_s_setprio(0);                                             \
} while (0)

#define BAR() __builtin_amdgcn_s_barrier()
#define LGW() do { asm volatile("s_waitcnt lgkmcnt(0)" ::: "memory");          \
                   __builtin_amdgcn_sched_barrier(0); } while (0)
#define VMW(st) do {                                                           \
    if (st) asm volatile("s_waitcnt vmcnt(4)" ::: "memory");                   \
    else    asm volatile("s_waitcnt vmcnt(0)" ::: "memory"); } while (0)

    // prologue: tile 0, issue order = consumption order
    STAGE_A(0, 0, 0);
    STAGE_B(0, 0, 0);
    STAGE_B(0, 1, 0);
    STAGE_A(0, 1, 0);
    asm volatile("s_waitcnt vmcnt(4)" ::: "memory");   // Ah0,Bh0 landed
    BAR();

    for (int kt = 0; kt < 8; ++kt) {
        const int cur = kt & 1, nxt = cur ^ 1;
        const bool st = kt < 7;
        // phase 1: Q(0,0) = Ah0 x Bh0 ; stage Ah0(kt+1)
        LDA(0, cur); LDB(bf0, 0, cur);
        if (st) STAGE_A(nxt, 0, kt + 1);
        VMW(st); BAR(); LGW();
        MMQ(bf0, 0, 0);
        BAR();
        // phase 2: Q(0,1) = Ah0 x Bh1 ; stage Bh0(kt+1)
        LDB(bf1, 1, cur);
        if (st) STAGE_B(nxt, 0, kt + 1);
        VMW(st); BAR(); LGW();
        MMQ(bf1, 0, 1);
        BAR();
        // phase 3: Q(1,1) = Ah1 x Bh1 ; stage Bh1(kt+1)
        LDA(1, cur);
        if (st) STAGE_B(nxt, 1, kt + 1);
        VMW(st); BAR(); LGW();
        MMQ(bf1, 1, 1);
        BAR();
        // phase 4: Q(1,0) = Ah1 x Bh0 ; stage Ah1(kt+1)
        if (st) STAGE_A(nxt, 1, kt + 1);
        VMW(st); BAR(); LGW();
        MMQ(bf0, 1, 0);
        BAR();
    }

#undef STAGE_A
#undef STAGE_B
#undef LDA
#undef LDB
#undef MMQ
#undef BAR
#undef LGW
#undef VMW

    int m0 = mt * 256 + wr * 128;
    int n0 = nt * 256 + wc * 64;

    if (MODE == 0) {
        // bounce C through dead LDS: per-wave 128x64 bf16 region (16 KB)
        short* region = (wid < 4) ? (&lA[0][0] + wid * 8192)
                                  : (&lB[0][0] + (wid - 4) * 8192);
#pragma unroll
        for (int a = 0; a < 4; a++) {
            int co = (a >> 1) * 32 + (a & 1) * 16;       // col offset of acc[.][a]
            int n = n0 + co + l15;
            float bv = bias[n];
            if (n < 512) bv *= QSCALE;
            int w16 = (co >> 3) + (l15 >> 3);
#pragma unroll
            for (int mi = 0; mi < 8; mi++)
#pragma unroll
                for (int r = 0; r < 4; r++) {
                    int row = mi * 16 + g * 4 + r;
                    region[row * 64 + ((w16 ^ (row & 7)) * 8) + (l15 & 7)] =
                        f2bf(acc[mi][a][r] + bv);
                }
        }
        // per-wave private region; compiler inserts lgkmcnt for RAW
#pragma unroll
        for (int p = 0; p < 2; p++) {
            int plane = (n0 >> 5) + p;                   // n/32 = which*16+head
            short* dst = (short*)C + ((size_t)plane * MP + m0) * 32;
#pragma unroll
            for (int i = 0; i < 8; i++) {
                int f = i * 64 + lane;
                int row = f >> 2, c = f & 3;
                s16x8 v = *(const s16x8*)(region + row * 64 +
                                          (((p * 4 + c) ^ (row & 7)) * 8));
                *(s16x8*)(dst + (size_t)f * 8) = v;      // coalesced 16B
            }
        }
    } else {
#pragma unroll
        for (int a = 0; a < 4; a++) {
            int co = (a >> 1) * 32 + (a & 1) * 16;
            int n = n0 + co + l15;
            float bv = bias[n];
#pragma unroll
            for (int mi = 0; mi < 8; mi++)
#pragma unroll
                for (int r = 0; r < 4; r++) {
                    int m = m0 + mi * 16 + g * 4 + r;
                    ((float*)C)[(size_t)m * 512 + n] = acc[mi][a][r] + bv;
                }
        }
    }
}

// ---------------- attention (LDS-free, 32x32 MFMA + shfl P-transpose) --------
// qkv head-major: [which][head][MP][32]. One wave per (window, head).
// bmF fragment-ordered: 16x dwordx4 bias loads, mask baked in (r14).
__global__ __launch_bounds__(256, 4) void k_attn(
    const short* __restrict__ qkv, const float* __restrict__ bmF,
    short* __restrict__ ao) {
    int wid = threadIdx.x >> 6, lane = threadIdx.x & 63;
    int p = blockIdx.x * 4 + wid;
    int w = p >> 4, head = p & 15;
    int l31 = lane & 31, h = lane >> 5;
    const size_t MP = M_TOTAL;

    const short* qb = qkv + ((size_t)head * MP + w * 49) * 32;
    const short* kb = qb + (size_t)16 * MP * 32;
    const short* vb = qb + (size_t)32 * MP * 32;

    // q/k fragments for S^T = K @ Q^T (A = K: row j; B = Q^T: col i; k = d)
    s16x8 qf[2][2], kf[2][2];
#pragma unroll
    for (int t = 0; t < 2; t++) {
        int row = t * 32 + l31;
#pragma unroll
        for (int s = 0; s < 2; s++) {
            qf[t][s] = *(const s16x8*)(qb + row * 32 + 16 * s + 8 * h);
            kf[t][s] = *(const s16x8*)(kb + row * 32 + 16 * s + 8 * h);
        }
    }

    // V B-fragments: lane: col d = l31, k-rows j = 16*jc + 8h + e
    union U8 { short s[8]; s16x8 v; };
    U8 vf[4];
#pragma unroll
    for (int jc = 0; jc < 4; jc++)
#pragma unroll
        for (int e = 0; e < 8; e++)
            vf[jc].s[e] = vb[(16 * jc + 8 * h + e) * 32 + l31];

    // S^T tiles: st[jt][it], elem r: j = 32jt + (r&3)+8(r>>2)+4h, i = 32it + l31
    f32x16 st[2][2] = {};
#pragma unroll
    for (int s = 0; s < 2; s++)
#pragma unroll
        for (int jt = 0; jt < 2; jt++)
#pragma unroll
            for (int it = 0; it < 2; it++)
                st[jt][it] = mfma32(kf[jt][s], qf[it][s], st[jt][it]);

    // + fragment-ordered (bias + mask), padding baked in: 4x dwordx4 per tile
    const float* bs = bmF + ((size_t)((w & 63) * NHEADS + head)) * 4096;
#pragma unroll
    for (int jt = 0; jt < 2; jt++)
#pragma unroll
        for (int it = 0; it < 2; it++) {
            const f32x4* bp = (const f32x4*)(bs + (((jt * 2 + it) * 64) + lane) * 16);
            f32x4 b0 = bp[0], b1 = bp[1], b2 = bp[2], b3 = bp[3];
#pragma unroll
            for (int r = 0; r < 4; r++) {
                st[jt][it][r]      += b0[r];
                st[jt][it][4 + r]  += b1[r];
                st[jt][it][8 + r]  += b2[r];
                st[jt][it][12 + r] += b3[r];
            }
        }

    // softmax over j (per column i): 32 in-lane values + cross-half xor32
    float inv[2];
#pragma unroll
    for (int it = 0; it < 2; it++) {
        float mx = -1e30f;
#pragma unroll
        for (int jt = 0; jt < 2; jt++)
#pragma unroll
            for (int r = 0; r < 16; r++) mx = fmaxf(mx, st[jt][it][r]);
        mx = fmaxf(mx, __shfl_xor(mx, 32));
        float sum = 0.f;
#pragma unroll
        for (int jt = 0; jt < 2; jt++)
#pragma unroll
            for (int r = 0; r < 16; r++) {
                float e = __expf(st[jt][it][r] - mx);
                st[jt][it][r] = e;
                sum += e;
            }
        sum += __shfl_xor(sum, 32);
        inv[it] = 1.0f / sum;
    }

    // PV: P A-frags built in-register (cvt_pk + shfl_xor(32) cross-half fetch)
    f32x16 oacc[2] = {};
#pragma unroll
    for (int jc = 0; jc < 4; jc++) {
        const int jt = jc >> 1, rb = 8 * (jc & 1);
#pragma unroll
        for (int it = 0; it < 2; it++) {
            float iv = inv[it];
            unsigned pk0  = cvtpk(st[jt][it][rb + 0] * iv, st[jt][it][rb + 1] * iv);
            unsigned pk0b = cvtpk(st[jt][it][rb + 2] * iv, st[jt][it][rb + 3] * iv);
            unsigned pk1  = cvtpk(st[jt][it][rb + 4] * iv, st[jt][it][rb + 5] * iv);
            unsigned pk1b = cvtpk(st[jt][it][rb + 6] * iv, st[jt][it][rb + 7] * iv);
            unsigned o0  = __shfl_xor(pk0, 32);
            unsigned o0b = __shfl_xor(pk0b, 32);
            unsigned o1  = __shfl_xor(pk1, 32);
            unsigned o1b = __shfl_xor(pk1b, 32);
            union { unsigned d[4]; s16x8 v; } pa;
            pa.d[0] = h ? o1  : pk0;
            pa.d[1] = h ? o1b : pk0b;
            pa.d[2] = h ? pk1 : o0;
            pa.d[3] = h ? pk1b : o0b;
            oacc[it] = mfma32(pa.v, vf[jc].v, oacc[it]);
        }
    }

    // store: col d = l31, row i = 32it + 4h + (r&3) + 8(r>>2)
    short* ob = ao + (size_t)w * 49 * 512 + head * 32 + l31;
#pragma unroll
    for (int it = 0; it < 2; it++)
#pragma unroll
        for (int r = 0; r < 16; r++) {
            int i = 32 * it + 4 * h + (r & 3) + 8 * (r >> 2);
            if (i < 49) ob[(size_t)i * 512] = f2bf(oacc[it][r]);
        }
}

// ---------------- launch ----------------

extern "C" void kernel_launch(void* const* d_in, const int* in_sizes, int n_in,
                              void* d_out, int out_size, void* d_ws, size_t ws_size,
                              hipStream_t stream) {
    const float* x     = (const float*)d_in[0];
    const float* mask  = (const float*)d_in[1];
    const float* Wqkv  = (const float*)d_in[2];
    const float* bqkv  = (const float*)d_in[3];
    const float* btab  = (const float*)d_in[4];
    const float* Wproj = (const float*)d_in[5];
    const float* bproj = (const float*)d_in[6];
    float* out = (float*)d_out;

    char* ws = (char*)d_ws;
    size_t off = 0;
    short* xb     = (short*)(ws + off); off += (size_t)M_TOTAL * 512 * 2;          // reused as ao
    short* qkvb   = (short*)(ws + off); off += (size_t)48 * M_TOTAL * 32 * 2 + 65536;  // head-major + pad
    short* Wqkvb  = (short*)(ws + off); off += (size_t)1536 * 512 * 2;
    short* Wprojb = (short*)(ws + off); off += (size_t)512 * 512 * 2;
    float* bmF    = (float*)(ws + off); off += (size_t)64 * NHEADS * 4 * 64 * 16 * 4;  // 16.8 MB
    short* ao = xb;   // alias: xb dead after qkv GEMM

    k_prep_x<<<2048, 256, 0, stream>>>(x, xb);
    k_prep_w<<<1536, 256, 0, stream>>>(Wqkv, Wqkvb, 1536 * 512, 512 * 512);
    k_prep_w<<<512, 256, 0, stream>>>(Wproj, Wprojb, 512 * 512, 0);
    k_prep_bm<<<4096, 256, 0, stream>>>(btab, mask, bmF);

    k_gemm<0><<<4704, 512, 0, stream>>>(xb, Wqkvb, bqkv, qkvb, 6, 4704);
    k_attn<<<16384, 256, 0, stream>>>(qkvb, bmF, ao);
    k_gemm<1><<<1568, 512, 0, stream>>>(ao, Wprojb, bproj, out, 2, 1568);
}